// Round 1
// baseline (592.228 us; speedup 1.0000x reference)
//
#include <hip/hip_runtime.h>

#define SEQ   2048
#define BATCH 4096
#define HD    32

// ---------------- fast device math ----------------
__device__ __forceinline__ float exp2_fast(float a) {
#if __has_builtin(__builtin_amdgcn_exp2f)
    return __builtin_amdgcn_exp2f(a);
#else
    return exp2f(a);
#endif
}

__device__ __forceinline__ float rcp_fast(float a) {
#if __has_builtin(__builtin_amdgcn_rcpf)
    return __builtin_amdgcn_rcpf(a);
#else
    return 1.0f / a;
#endif
}

// tanh(x) = sign(x) * (1 - e^{-2|x|}) / (1 + e^{-2|x|}),  e^{-2|x|} = 2^{-2*log2(e)*|x|}
__device__ __forceinline__ float fast_tanh(float v) {
    float ax = fabsf(v);
    float e  = exp2_fast(ax * -2.8853900817779268f);
    float r  = (1.0f - e) * rcp_fast(1.0f + e);
    return copysignf(r, v);
}

// DPP row_shr add helper: returns value from lane (lane - N) within the 16-lane row, 0 if shifted in.
template <int CTRL>
__device__ __forceinline__ float dpp_mov0(float v) {
    return __int_as_float(
        __builtin_amdgcn_update_dpp(0, __float_as_int(v), CTRL, 0xF, 0xF, false));
}

// ---------------- kernel ----------------
// 16 lanes per batch element; lane s owns h rows 2s, 2s+1.
// h state lives in LDS (36-float padded slot per element, wave-private groups).
// Per step: 8x ds_read_b128 broadcast of all 32 h, 64 fp32 FMAs (8 indep chains),
// 2x tanh, ds_write_b64 of own h, DPP row reduction for the output dot.
__global__ __launch_bounds__(256) void rnn_elman_kernel(
    const float* __restrict__ x, const float* __restrict__ hidden,
    const float* __restrict__ W_ih, const float* __restrict__ b_ih,
    const float* __restrict__ W_hh, const float* __restrict__ b_hh,
    const float* __restrict__ W_fc, const float* __restrict__ b_fc,
    float* __restrict__ out)
{
    __shared__ float sh[16 * 36];   // 16 elements/block, padded stride 36 (bank-conflict-free)

    const int tid = threadIdx.x;
    const int s   = tid & 15;        // lane within element group
    const int eb  = tid >> 4;        // element within block (0..15)
    const int e   = blockIdx.x * 16 + eb;   // global batch element
    const int r0  = 2 * s;
    const int r1  = 2 * s + 1;

    // ---- weights into registers ----
    float4 w0[8], w1[8];
    {
        const float4* W0 = reinterpret_cast<const float4*>(W_hh + r0 * HD);
        const float4* W1 = reinterpret_cast<const float4*>(W_hh + r1 * HD);
        #pragma unroll
        for (int k = 0; k < 8; ++k) { w0[k] = W0[k]; w1[k] = W1[k]; }
    }
    const float wih0  = W_ih[r0], wih1 = W_ih[r1];
    const float bias0 = b_ih[r0] + b_hh[r0];
    const float bias1 = b_ih[r1] + b_hh[r1];
    const float wfc0  = W_fc[r0], wfc1 = W_fc[r1];
    const float bfc   = b_fc[0];

    // ---- init hidden state into LDS ----
    float* slot = sh + eb * 36;
    reinterpret_cast<float2*>(slot)[s] =
        make_float2(hidden[e * HD + r0], hidden[e * HD + r1]);
    __builtin_amdgcn_wave_barrier();

    float4 hb[8];
    #pragma unroll
    for (int k = 0; k < 8; ++k) hb[k] = reinterpret_cast<const float4*>(slot)[k];

    // ---- x prefetch pipe (distance 4) ----
    float xq0 = x[0 * BATCH + e];
    float xq1 = x[1 * BATCH + e];
    float xq2 = x[2 * BATCH + e];
    float xq3 = x[3 * BATCH + e];

    #pragma unroll 4
    for (int t = 0; t < SEQ; ++t) {
        const float xv = xq0;
        xq0 = xq1; xq1 = xq2; xq2 = xq3;
        {
            int tt = t + 4; tt = tt < SEQ - 1 ? tt : SEQ - 1;   // clamped, always in bounds
            xq3 = x[tt * BATCH + e];
        }

        // ---- matvec: 8 independent FMA chains of depth 8 ----
        float a0a = fmaf(xv, wih0, bias0);
        float a1a = fmaf(xv, wih1, bias1);
        float a0b = 0.f, a0c = 0.f, a0d = 0.f;
        float a1b = 0.f, a1c = 0.f, a1d = 0.f;
        #pragma unroll
        for (int k = 0; k < 8; ++k) {
            const float4 h4 = hb[k];
            const float4 ww = w0[k];
            const float4 vv = w1[k];
            a0a = fmaf(ww.x, h4.x, a0a);
            a0b = fmaf(ww.y, h4.y, a0b);
            a0c = fmaf(ww.z, h4.z, a0c);
            a0d = fmaf(ww.w, h4.w, a0d);
            a1a = fmaf(vv.x, h4.x, a1a);
            a1b = fmaf(vv.y, h4.y, a1b);
            a1c = fmaf(vv.z, h4.z, a1c);
            a1d = fmaf(vv.w, h4.w, a1d);
        }
        const float z0 = (a0a + a0b) + (a0c + a0d);
        const float z1 = (a1a + a1b) + (a1c + a1d);

        const float h0 = fast_tanh(z0);
        const float h1 = fast_tanh(z1);

        // ---- publish own h, refetch full state for next step ----
        reinterpret_cast<float2*>(slot)[s] = make_float2(h0, h1);
        __builtin_amdgcn_wave_barrier();
        #pragma unroll
        for (int k = 0; k < 8; ++k) hb[k] = reinterpret_cast<const float4*>(slot)[k];

        // ---- output projection: reduce over the 16-lane row via DPP (VALU pipe) ----
        float p = fmaf(h0, wfc0, h1 * wfc1);
        p += dpp_mov0<0x111>(p);   // row_shr:1
        p += dpp_mov0<0x112>(p);   // row_shr:2
        p += dpp_mov0<0x114>(p);   // row_shr:4
        p += dpp_mov0<0x118>(p);   // row_shr:8  -> lane 15 of each row holds the full sum
        if (s == 15) out[t * BATCH + e] = p + bfc;
    }
}

// ---------------- launch ----------------
extern "C" void kernel_launch(void* const* d_in, const int* in_sizes, int n_in,
                              void* d_out, int out_size, void* d_ws, size_t ws_size,
                              hipStream_t stream) {
    const float* x    = (const float*)d_in[0];
    const float* hid  = (const float*)d_in[1];
    const float* W_ih = (const float*)d_in[2];
    const float* b_ih = (const float*)d_in[3];
    const float* W_hh = (const float*)d_in[4];
    const float* b_hh = (const float*)d_in[5];
    const float* W_fc = (const float*)d_in[6];
    const float* b_fc = (const float*)d_in[7];
    float* out = (float*)d_out;

    dim3 grid(BATCH / 16);   // 256 blocks -> 1 block/CU
    dim3 block(256);         // 16 elements/block, 4 waves
    rnn_elman_kernel<<<grid, block, 0, stream>>>(x, hid, W_ih, b_ih, W_hh, b_hh,
                                                 W_fc, b_fc, out);
}